// Round 3
// baseline (556.719 us; speedup 1.0000x reference)
//
#include <hip/hip_runtime.h>

#define N_NODES 100000
#define N_EDGES 1600000
#define IN_CH   64
#define HID_CH  64
#define OUT_CH  128
#define TILE    128
#define N_TILES (N_EDGES / TILE)   // 12500 exactly

typedef __attribute__((ext_vector_type(8))) __bf16 bf16x8;
typedef __attribute__((ext_vector_type(4))) float  f32x4;

__device__ __forceinline__ unsigned short f2bf(float f) {
    union { float f; unsigned int i; } c;
    c.f = f;
    unsigned int u = c.i;
    unsigned int r = (u + 0x7FFFu + ((u >> 16) & 1u)) >> 16;   // RNE
    return (unsigned short)r;
}

// fp32 x[N_NODES][64] -> bf16 bits (so edge gather is 16B/lane contiguous)
__global__ void x_to_bf16(const float* __restrict__ xf,
                          unsigned short* __restrict__ xb) {
    int i = blockIdx.x * blockDim.x + threadIdx.x;   // vec4 index, exact fit
    float4 v = reinterpret_cast<const float4*>(xf)[i];
    ushort4 o;
    o.x = f2bf(v.x); o.y = f2bf(v.y); o.z = f2bf(v.z); o.w = f2bf(v.w);
    reinterpret_cast<ushort4*>(xb)[i] = o;
}

// Edge kernel: layer 1 only. h_e = relu([x_dst|x_src|ea] @ W1 + b1), then
// masked scatter-add of the 64-ch hidden into hsum[dst] (fp32 atomics) plus
// per-edge count into cnt[dst]. Layer 2 is applied AFTER the segment sum
// (linearity: sum_e (p_e @ W2 + b2) = (sum_e p_e) @ W2 + c_n * b2) — this
// halves the atomic-dword count, which is the measured bottleneck
// (301 G dword-atomics/s ~= L2 atomic ceiling in round 2).
__global__ __launch_bounds__(256, 4) void gnn_edge_hidden(
    const float*          __restrict__ x,     // [N_NODES][64] fp32 (node type col 0)
    const unsigned short* __restrict__ xb,    // [N_NODES][64] bf16 bits
    const int*            __restrict__ eidx,  // [2][N_EDGES]
    const float*          __restrict__ ea,    // [N_EDGES][3]
    const float*          __restrict__ W1,    // [131][64]
    const float*          __restrict__ b1,    // [64]
    float*                __restrict__ hsum,  // [N_NODES][64] fp32 accum
    float*                __restrict__ cnt)   // [N_NODES] masked-edge counts
{
    // +8-short row padding keeps ds_read_b128 bank-balanced
    __shared__ __align__(16) unsigned short W1T[64][136];   // W1T[n][k]=W1[k][n], k<128
    __shared__ float w1tail[4][64];   // W1[128],W1[129],W1[130], b1 (fp32)
    __shared__ float eas[128][4];
    __shared__ float masks[128];
    __shared__ int   dsts[128];
    __shared__ int   srcs[128];

    const int tid  = threadIdx.x;
    const int wave = tid >> 6;
    const int lane = tid & 63;
    const int q    = lane >> 4;   // quad 0..3
    const int m16  = lane & 15;

    // ---- stage W1 once per persistent block (fp32 -> bf16) ----
    for (int idx = tid; idx < 128 * 64; idx += 256) {
        int k = idx >> 6, n = idx & 63;
        W1T[n][k] = f2bf(W1[idx]);
    }
    if (tid < 64) {
        w1tail[0][tid] = W1[128 * 64 + tid];
        w1tail[1][tid] = W1[129 * 64 + tid];
        w1tail[2][tid] = W1[130 * 64 + tid];
        w1tail[3][tid] = b1[tid];
    }

    for (int t = blockIdx.x; t < N_TILES; t += gridDim.x) {
        __syncthreads();   // covers weight staging (1st iter) + LDS WAR reuse
        if (tid < 128) {
            int e = t * TILE + tid;
            int s = eidx[e];
            int d = eidx[N_EDGES + e];
            srcs[tid] = s;
            dsts[tid] = d;
            float a0 = ea[e * 3 + 0];
            float a1 = ea[e * 3 + 1];
            float a2 = ea[e * 3 + 2];
            eas[tid][0] = a0; eas[tid][1] = a1; eas[tid][2] = a2;
            float nt = x[(size_t)s * IN_CH];   // node type of source (exact fp32)
            float mk;
            if (nt == 0.0f)      mk = (a0 < 0.5f) ? 1.0f : 0.0f;
            else if (nt == 1.0f) mk = (a0 < 0.3f) ? 1.0f : 0.0f;
            else                 mk = 1.0f;
            masks[tid] = mk;
            if (mk != 0.0f) unsafeAtomicAdd(&cnt[d], 1.0f);
        }
        __syncthreads();

        const int ebase = wave * 32;

        // ---- acc init: b1 + ea @ W1[128:131] (fp32 VALU) ----
        f32x4 acc1[2][4];
#pragma unroll
        for (int mt = 0; mt < 2; ++mt) {
            float e0[4], e1[4], e2[4];
#pragma unroll
            for (int r = 0; r < 4; ++r) {
                int el = ebase + mt * 16 + q * 4 + r;   // C-layout row
                e0[r] = eas[el][0]; e1[r] = eas[el][1]; e2[r] = eas[el][2];
            }
#pragma unroll
            for (int nt = 0; nt < 4; ++nt) {
                int n = nt * 16 + m16;                  // C-layout col
                float t0 = w1tail[0][n], t1 = w1tail[1][n];
                float t2 = w1tail[2][n], bb = w1tail[3][n];
#pragma unroll
                for (int r = 0; r < 4; ++r)
                    acc1[mt][nt][r] = bb + e0[r] * t0 + e1[r] * t1 + e2[r] * t2;
            }
        }

        // K=128 over [x_dst (kc 0,1) | x_src (kc 2,3)], A-frags from global bf16
#pragma unroll
        for (int kc = 0; kc < 4; ++kc) {
            bf16x8 af[2];
#pragma unroll
            for (int mt = 0; mt < 2; ++mt) {
                int el   = ebase + mt * 16 + m16;       // A-layout row m=lane&15
                int node = (kc < 2) ? dsts[el] : srcs[el];
                af[mt] = *reinterpret_cast<const bf16x8*>(
                    xb + (size_t)node * IN_CH + (kc & 1) * 32 + q * 8);
            }
#pragma unroll
            for (int nt = 0; nt < 4; ++nt) {
                bf16x8 bfr = *reinterpret_cast<const bf16x8*>(
                    &W1T[nt * 16 + m16][kc * 32 + q * 8]);
                acc1[0][nt] = __builtin_amdgcn_mfma_f32_16x16x32_bf16(af[0], bfr, acc1[0][nt], 0, 0, 0);
                acc1[1][nt] = __builtin_amdgcn_mfma_f32_16x16x32_bf16(af[1], bfr, acc1[1][nt], 0, 0, 0);
            }
        }

        // ---- epilogue: masked relu(h) -> fp32 atomic scatter into hsum ----
#pragma unroll
        for (int mt = 0; mt < 2; ++mt) {
            float mk[4]; int dd[4];
#pragma unroll
            for (int r = 0; r < 4; ++r) {
                int el = ebase + mt * 16 + q * 4 + r;   // C-layout row
                mk[r] = masks[el];
                dd[r] = dsts[el];
            }
#pragma unroll
            for (int nt = 0; nt < 4; ++nt) {
                int col = nt * 16 + m16;                // C-layout col
#pragma unroll
                for (int r = 0; r < 4; ++r) {
                    if (mk[r] != 0.0f) {
                        float v = acc1[mt][nt][r];
                        v = v > 0.0f ? v : 0.0f;
                        unsafeAtomicAdd(&hsum[(size_t)dd[r] * HID_CH + col], v);
                    }
                }
            }
        }
    }
}

// Node kernel: out[n] = relu(hsum[n] @ W2 + cnt[n]*b2), all fp32.
// One wave per node; lane l computes cols l and l+64.
__global__ __launch_bounds__(256, 4) void gnn_node_out(
    const float* __restrict__ hsum,   // [N_NODES][64]
    const float* __restrict__ cnt,    // [N_NODES]
    const float* __restrict__ W2,     // [64][128]
    const float* __restrict__ b2,     // [128]
    float*       __restrict__ out)    // [N_NODES][128]
{
    __shared__ float W2s[64][128];
    __shared__ float b2s[128];
    const int tid = threadIdx.x;
    for (int idx = tid; idx < 64 * 128; idx += 256)
        W2s[idx >> 7][idx & 127] = W2[idx];
    if (tid < 128) b2s[tid] = b2[tid];
    __syncthreads();

    const int wave = tid >> 6;
    const int lane = tid & 63;
    const int nw   = gridDim.x * 4;

    for (int n = blockIdx.x * 4 + wave; n < N_NODES; n += nw) {
        const float* hr = hsum + (size_t)n * HID_CH;
        float c  = cnt[n];
        float a0 = c * b2s[lane];
        float a1 = c * b2s[lane + 64];
        float hv = hr[lane];   // lane l holds h[l]; broadcast via shfl
#pragma unroll
        for (int k = 0; k < 64; ++k) {
            float hk = __shfl(hv, k);
            a0 += hk * W2s[k][lane];
            a1 += hk * W2s[k][lane + 64];
        }
        out[(size_t)n * OUT_CH + lane]      = a0 > 0.0f ? a0 : 0.0f;
        out[(size_t)n * OUT_CH + lane + 64] = a1 > 0.0f ? a1 : 0.0f;
    }
}

extern "C" void kernel_launch(void* const* d_in, const int* in_sizes, int n_in,
                              void* d_out, int out_size, void* d_ws, size_t ws_size,
                              hipStream_t stream) {
    const float* x  = (const float*)d_in[0];
    const int*   ei = (const int*)d_in[1];
    const float* ea = (const float*)d_in[2];
    const float* W1 = (const float*)d_in[3];
    const float* b1 = (const float*)d_in[4];
    const float* W2 = (const float*)d_in[5];
    const float* b2 = (const float*)d_in[6];
    float* out = (float*)d_out;

    // ws layout: [hsum 25.6MB][cnt 0.4MB][xb 12.8MB]  (38.8MB total)
    float* hsum = (float*)d_ws;
    float* cnt  = hsum + (size_t)N_NODES * HID_CH;
    unsigned short* xb = (unsigned short*)(cnt + N_NODES);

    // zero hsum+cnt (contiguous); re-poisoned to 0xAA before every call
    hipMemsetAsync(hsum, 0, (size_t)(N_NODES * HID_CH + N_NODES) * sizeof(float), stream);

    // fp32 -> bf16 conversion of x (6.4M elems, vec4, exact fit)
    x_to_bf16<<<(N_NODES * IN_CH) / 4 / 256, 256, 0, stream>>>(x, xb);

    // 1024 blocks = 4 blocks/CU (22KB LDS) — edge MLP layer 1 + hidden scatter
    gnn_edge_hidden<<<1024, 256, 0, stream>>>(x, xb, ei, ea, W1, b1, hsum, cnt);

    // node-level layer 2 + relu, writes d_out directly (no pre-zero needed)
    gnn_node_out<<<1024, 256, 0, stream>>>(hsum, cnt, W2, b2, out);
}

// Round 4
// 378.958 us; speedup vs baseline: 1.4691x; 1.4691x over previous
//
#include <hip/hip_runtime.h>

#define N_NODES 100000
#define N_EDGES 1600000
#define IN_CH   64
#define HID_CH  64
#define OUT_CH  128
#define TILE    128
#define N_TILES (N_EDGES / TILE)   // 12500 exactly

typedef __attribute__((ext_vector_type(8))) __bf16 bf16x8;
typedef __attribute__((ext_vector_type(4))) float  f32x4;

__device__ __forceinline__ unsigned short f2bf(float f) {
    union { float f; unsigned int i; } c;
    c.f = f;
    unsigned int u = c.i;
    unsigned int r = (u + 0x7FFFu + ((u >> 16) & 1u)) >> 16;   // RNE
    return (unsigned short)r;
}

// fp32 x[N_NODES][64] -> bf16 bits (so edge gather is 16B/lane contiguous)
__global__ void x_to_bf16(const float* __restrict__ xf,
                          unsigned short* __restrict__ xb) {
    int i = blockIdx.x * blockDim.x + threadIdx.x;   // vec4 index, exact fit
    float4 v = reinterpret_cast<const float4*>(xf)[i];
    ushort4 o;
    o.x = f2bf(v.x); o.y = f2bf(v.y); o.z = f2bf(v.z); o.w = f2bf(v.w);
    reinterpret_cast<ushort4*>(xb)[i] = o;
}

// Edge kernel: layer 1 only. h_e = relu([x_dst|x_src|ea] @ W1 + b1), then
// masked scatter-add of the 64-ch hidden into hsum[dst] (fp32 atomics) plus
// per-edge count into cnt[dst]. Layer 2 commutes with the segment-sum.
__global__ __launch_bounds__(256, 4) void gnn_edge_hidden(
    const float*          __restrict__ x,     // [N_NODES][64] fp32 (node type col 0)
    const unsigned short* __restrict__ xb,    // [N_NODES][64] bf16 bits
    const int*            __restrict__ eidx,  // [2][N_EDGES]
    const float*          __restrict__ ea,    // [N_EDGES][3]
    const float*          __restrict__ W1,    // [131][64]
    const float*          __restrict__ b1,    // [64]
    float*                __restrict__ hsum,  // [N_NODES][64] fp32 accum
    float*                __restrict__ cnt)   // [N_NODES] masked-edge counts
{
    __shared__ __align__(16) unsigned short W1T[64][136];   // W1T[n][k]=W1[k][n], k<128
    __shared__ float w1tail[4][64];   // W1[128],W1[129],W1[130], b1 (fp32)
    __shared__ float eas[128][4];
    __shared__ float masks[128];
    __shared__ int   dsts[128];
    __shared__ int   srcs[128];

    const int tid  = threadIdx.x;
    const int wave = tid >> 6;
    const int lane = tid & 63;
    const int q    = lane >> 4;   // quad 0..3
    const int m16  = lane & 15;

    // ---- stage W1 once per persistent block (fp32 -> bf16) ----
    for (int idx = tid; idx < 128 * 64; idx += 256) {
        int k = idx >> 6, n = idx & 63;
        W1T[n][k] = f2bf(W1[idx]);
    }
    if (tid < 64) {
        w1tail[0][tid] = W1[128 * 64 + tid];
        w1tail[1][tid] = W1[129 * 64 + tid];
        w1tail[2][tid] = W1[130 * 64 + tid];
        w1tail[3][tid] = b1[tid];
    }

    for (int t = blockIdx.x; t < N_TILES; t += gridDim.x) {
        __syncthreads();   // covers weight staging (1st iter) + LDS WAR reuse
        if (tid < 128) {
            int e = t * TILE + tid;
            int s = eidx[e];
            int d = eidx[N_EDGES + e];
            srcs[tid] = s;
            dsts[tid] = d;
            float a0 = ea[e * 3 + 0];
            float a1 = ea[e * 3 + 1];
            float a2 = ea[e * 3 + 2];
            eas[tid][0] = a0; eas[tid][1] = a1; eas[tid][2] = a2;
            float nt = x[(size_t)s * IN_CH];   // node type of source (exact fp32)
            float mk;
            if (nt == 0.0f)      mk = (a0 < 0.5f) ? 1.0f : 0.0f;
            else if (nt == 1.0f) mk = (a0 < 0.3f) ? 1.0f : 0.0f;
            else                 mk = 1.0f;
            masks[tid] = mk;
            if (mk != 0.0f) unsafeAtomicAdd(&cnt[d], 1.0f);
        }
        __syncthreads();

        const int ebase = wave * 32;

        // ---- acc init: b1 + ea @ W1[128:131] (fp32 VALU) ----
        f32x4 acc1[2][4];
#pragma unroll
        for (int mt = 0; mt < 2; ++mt) {
            float e0[4], e1[4], e2[4];
#pragma unroll
            for (int r = 0; r < 4; ++r) {
                int el = ebase + mt * 16 + q * 4 + r;   // C-layout row
                e0[r] = eas[el][0]; e1[r] = eas[el][1]; e2[r] = eas[el][2];
            }
#pragma unroll
            for (int nt = 0; nt < 4; ++nt) {
                int n = nt * 16 + m16;                  // C-layout col
                float t0 = w1tail[0][n], t1 = w1tail[1][n];
                float t2 = w1tail[2][n], bb = w1tail[3][n];
#pragma unroll
                for (int r = 0; r < 4; ++r)
                    acc1[mt][nt][r] = bb + e0[r] * t0 + e1[r] * t1 + e2[r] * t2;
            }
        }

        // K=128 over [x_dst (kc 0,1) | x_src (kc 2,3)], A-frags from global bf16
#pragma unroll
        for (int kc = 0; kc < 4; ++kc) {
            bf16x8 af[2];
#pragma unroll
            for (int mt = 0; mt < 2; ++mt) {
                int el   = ebase + mt * 16 + m16;       // A-layout row m=lane&15
                int node = (kc < 2) ? dsts[el] : srcs[el];
                af[mt] = *reinterpret_cast<const bf16x8*>(
                    xb + (size_t)node * IN_CH + (kc & 1) * 32 + q * 8);
            }
#pragma unroll
            for (int nt = 0; nt < 4; ++nt) {
                bf16x8 bfr = *reinterpret_cast<const bf16x8*>(
                    &W1T[nt * 16 + m16][kc * 32 + q * 8]);
                acc1[0][nt] = __builtin_amdgcn_mfma_f32_16x16x32_bf16(af[0], bfr, acc1[0][nt], 0, 0, 0);
                acc1[1][nt] = __builtin_amdgcn_mfma_f32_16x16x32_bf16(af[1], bfr, acc1[1][nt], 0, 0, 0);
            }
        }

        // ---- epilogue: masked relu(h) -> fp32 atomic scatter into hsum ----
#pragma unroll
        for (int mt = 0; mt < 2; ++mt) {
            float mk[4]; int dd[4];
#pragma unroll
            for (int r = 0; r < 4; ++r) {
                int el = ebase + mt * 16 + q * 4 + r;   // C-layout row
                mk[r] = masks[el];
                dd[r] = dsts[el];
            }
#pragma unroll
            for (int nt = 0; nt < 4; ++nt) {
                int col = nt * 16 + m16;                // C-layout col
#pragma unroll
                for (int r = 0; r < 4; ++r) {
                    if (mk[r] != 0.0f) {
                        float v = acc1[mt][nt][r];
                        v = v > 0.0f ? v : 0.0f;
                        unsafeAtomicAdd(&hsum[(size_t)dd[r] * HID_CH + col], v);
                    }
                }
            }
        }
    }
}

// Node kernel (MFMA): out[n] = relu(hsum[n] @ W2 + cnt[n]*b2).
// One wave = 32 nodes (2 m-tiles), N=128 (8 n-tiles), K=64 (2 chunks).
// A-fragments: 8 fp32 of the hsum row -> bf16 in-register. W2^T bf16 in LDS.
// Replaces the round-3 shfl-broadcast kernel (latency-bound, ~200us).
__global__ __launch_bounds__(256, 4) void gnn_node_out(
    const float* __restrict__ hsum,   // [N_NODES][64]
    const float* __restrict__ cnt,    // [N_NODES]
    const float* __restrict__ W2,     // [64][128]
    const float* __restrict__ b2,     // [128]
    float*       __restrict__ out)    // [N_NODES][128]
{
    __shared__ __align__(16) unsigned short W2T[128][72];  // W2T[n][k]=W2[k][n]
    __shared__ float b2s[128];

    const int tid  = threadIdx.x;
    const int wave = tid >> 6;
    const int lane = tid & 63;
    const int q    = lane >> 4;
    const int m16  = lane & 15;

    for (int idx = tid; idx < 64 * 128; idx += 256) {
        int k = idx >> 7, n = idx & 127;
        W2T[n][k] = f2bf(W2[idx]);
    }
    if (tid < 128) b2s[tid] = b2[tid];
    __syncthreads();

    const int nodeBase = (blockIdx.x * 4 + wave) * 32;
    if (nodeBase >= N_NODES) return;   // tail waves (no barriers below)

    f32x4 acc[2][8];
#pragma unroll
    for (int mt = 0; mt < 2; ++mt)
#pragma unroll
        for (int nt = 0; nt < 8; ++nt)
            acc[mt][nt] = (f32x4){0.0f, 0.0f, 0.0f, 0.0f};

#pragma unroll
    for (int kc = 0; kc < 2; ++kc) {
        bf16x8 af[2];
#pragma unroll
        for (int mt = 0; mt < 2; ++mt) {
            int node = nodeBase + mt * 16 + m16;     // A-layout row (may run
            const float* hp = hsum + (size_t)node * HID_CH + kc * 32 + q * 8;
            float4 h0 = *reinterpret_cast<const float4*>(hp);      // OOB rows
            float4 h1 = *reinterpret_cast<const float4*>(hp + 4);  // land in ws)
            union { bf16x8 v; unsigned short u[8]; } r;
            r.u[0] = f2bf(h0.x); r.u[1] = f2bf(h0.y);
            r.u[2] = f2bf(h0.z); r.u[3] = f2bf(h0.w);
            r.u[4] = f2bf(h1.x); r.u[5] = f2bf(h1.y);
            r.u[6] = f2bf(h1.z); r.u[7] = f2bf(h1.w);
            af[mt] = r.v;
        }
#pragma unroll
        for (int nt = 0; nt < 8; ++nt) {
            bf16x8 bfr = *reinterpret_cast<const bf16x8*>(
                &W2T[nt * 16 + m16][kc * 32 + q * 8]);
            acc[0][nt] = __builtin_amdgcn_mfma_f32_16x16x32_bf16(af[0], bfr, acc[0][nt], 0, 0, 0);
            acc[1][nt] = __builtin_amdgcn_mfma_f32_16x16x32_bf16(af[1], bfr, acc[1][nt], 0, 0, 0);
        }
    }

    // epilogue: + cnt*b2, relu, store (C-layout: row=q*4+r, col=nt*16+m16)
#pragma unroll
    for (int mt = 0; mt < 2; ++mt) {
        float cc[4]; int nn[4];
#pragma unroll
        for (int r = 0; r < 4; ++r) {
            nn[r] = nodeBase + mt * 16 + q * 4 + r;
            cc[r] = (nn[r] < N_NODES) ? cnt[nn[r]] : 0.0f;
        }
#pragma unroll
        for (int nt = 0; nt < 8; ++nt) {
            int col = nt * 16 + m16;
            float bb = b2s[col];
#pragma unroll
            for (int r = 0; r < 4; ++r) {
                if (nn[r] < N_NODES) {
                    float v = acc[mt][nt][r] + cc[r] * bb;
                    out[(size_t)nn[r] * OUT_CH + col] = v > 0.0f ? v : 0.0f;
                }
            }
        }
    }
}

extern "C" void kernel_launch(void* const* d_in, const int* in_sizes, int n_in,
                              void* d_out, int out_size, void* d_ws, size_t ws_size,
                              hipStream_t stream) {
    const float* x  = (const float*)d_in[0];
    const int*   ei = (const int*)d_in[1];
    const float* ea = (const float*)d_in[2];
    const float* W1 = (const float*)d_in[3];
    const float* b1 = (const float*)d_in[4];
    const float* W2 = (const float*)d_in[5];
    const float* b2 = (const float*)d_in[6];
    float* out = (float*)d_out;

    // ws layout: [hsum 25.6MB][cnt 0.4MB][xb 12.8MB]  (38.8MB total)
    float* hsum = (float*)d_ws;
    float* cnt  = hsum + (size_t)N_NODES * HID_CH;
    unsigned short* xb = (unsigned short*)(cnt + N_NODES);

    // zero hsum+cnt (contiguous); ws re-poisoned to 0xAA before every call
    hipMemsetAsync(hsum, 0, (size_t)(N_NODES * HID_CH + N_NODES) * sizeof(float), stream);

    // fp32 -> bf16 conversion of x (6.4M elems, vec4, exact fit)
    x_to_bf16<<<(N_NODES * IN_CH) / 4 / 256, 256, 0, stream>>>(x, xb);

    // 1024 blocks = 4 blocks/CU (22KB LDS) — edge MLP layer 1 + hidden scatter
    gnn_edge_hidden<<<1024, 256, 0, stream>>>(x, xb, ei, ea, W1, b1, hsum, cnt);

    // node-level layer 2 + relu via MFMA: 128 nodes/block, 782 blocks
    gnn_node_out<<<(N_NODES + 127) / 128, 256, 0, stream>>>(hsum, cnt, W2, b2, out);
}

// Round 5
// 281.444 us; speedup vs baseline: 1.9781x; 1.3465x over previous
//
#include <hip/hip_runtime.h>

#define N_NODES 100000
#define N_EDGES 1600000
#define IN_CH   64
#define HID_CH  64
#define OUT_CH  128
#define TILE    128
#define N_TILES (N_EDGES / TILE)   // 12500 exactly

typedef __attribute__((ext_vector_type(8))) __bf16    bf16x8;
typedef __attribute__((ext_vector_type(4))) float     f32x4;
typedef __attribute__((ext_vector_type(2))) _Float16  f16x2;
typedef __attribute__((ext_vector_type(8))) _Float16  f16x8;

__device__ __forceinline__ unsigned short f2bf(float f) {
    union { float f; unsigned int i; } c;
    c.f = f;
    unsigned int u = c.i;
    unsigned int r = (u + 0x7FFFu + ((u >> 16) & 1u)) >> 16;   // RNE
    return (unsigned short)r;
}

// packed fp16 atomic add (global_atomic_pk_add_f16, gfx90a+)
__device__ __forceinline__ void atomic_pk_add_f16(unsigned int* addr, f16x2 val) {
    typedef __attribute__((address_space(1))) f16x2 gf16x2;
    __builtin_amdgcn_global_atomic_fadd_v2f16((gf16x2*)(void*)addr, val);
}

// fused prep: x fp32->bf16 convert + zero hsum(fp16) + zero cnt
// items: [0,1.6M): x float4 convert; [1.6M,2.4M): hsum uint4 zero;
//        [2.4M,2.425M): cnt float4 zero
__global__ void gnn_prep(const float* __restrict__ xf,
                         unsigned short* __restrict__ xb,
                         uint4* __restrict__ hz,      // hsum as uint4 (800k)
                         float4* __restrict__ cz) {   // cnt  as float4 (25k)
    int i = blockIdx.x * blockDim.x + threadIdx.x;
    if (i < 1600000) {
        float4 v = reinterpret_cast<const float4*>(xf)[i];
        ushort4 o;
        o.x = f2bf(v.x); o.y = f2bf(v.y); o.z = f2bf(v.z); o.w = f2bf(v.w);
        reinterpret_cast<ushort4*>(xb)[i] = o;
    } else if (i < 2400000) {
        hz[i - 1600000] = (uint4){0u, 0u, 0u, 0u};
    } else if (i < 2425000) {
        cz[i - 2400000] = (float4){0.f, 0.f, 0.f, 0.f};
    }
}

// Edge kernel: h_e = relu([x_dst|x_src|ea] @ W1 + b1); masked scatter of the
// 64-ch hidden into hsum[dst] as PACKED fp16 atomics (2 ch/dword), skipping
// all-zero pairs (~25% post-relu). hsum memory channel order is permuted:
// dword d<16 holds channels (d, d+16); d>=16 holds (d+16, d+32) — the node
// kernel permutes W2's rows identically, so no un-permute pass is needed.
__global__ __launch_bounds__(256, 4) void gnn_edge_hidden(
    const float*          __restrict__ x,     // [N_NODES][64] fp32 (node type col 0)
    const unsigned short* __restrict__ xb,    // [N_NODES][64] bf16 bits
    const int*            __restrict__ eidx,  // [2][N_EDGES]
    const float*          __restrict__ ea,    // [N_EDGES][3]
    const float*          __restrict__ W1,    // [131][64]
    const float*          __restrict__ b1,    // [64]
    unsigned int*         __restrict__ hsum,  // [N_NODES][32] packed-f16 pairs
    float*                __restrict__ cnt)   // [N_NODES] masked-edge counts
{
    __shared__ __align__(16) unsigned short W1T[64][136];   // W1T[n][k]=W1[k][n], k<128
    __shared__ float w1tail[4][64];   // W1[128],W1[129],W1[130], b1 (fp32)
    __shared__ float eas[128][4];
    __shared__ float masks[128];
    __shared__ int   dsts[128];
    __shared__ int   srcs[128];

    const int tid  = threadIdx.x;
    const int wave = tid >> 6;
    const int lane = tid & 63;
    const int q    = lane >> 4;   // quad 0..3
    const int m16  = lane & 15;

    // ---- stage W1 once per persistent block (fp32 -> bf16) ----
    for (int idx = tid; idx < 128 * 64; idx += 256) {
        int k = idx >> 6, n = idx & 63;
        W1T[n][k] = f2bf(W1[idx]);
    }
    if (tid < 64) {
        w1tail[0][tid] = W1[128 * 64 + tid];
        w1tail[1][tid] = W1[129 * 64 + tid];
        w1tail[2][tid] = W1[130 * 64 + tid];
        w1tail[3][tid] = b1[tid];
    }

    for (int t = blockIdx.x; t < N_TILES; t += gridDim.x) {
        __syncthreads();   // covers weight staging (1st iter) + LDS WAR reuse
        if (tid < 128) {
            int e = t * TILE + tid;
            int s = eidx[e];
            int d = eidx[N_EDGES + e];
            srcs[tid] = s;
            dsts[tid] = d;
            float a0 = ea[e * 3 + 0];
            float a1 = ea[e * 3 + 1];
            float a2 = ea[e * 3 + 2];
            eas[tid][0] = a0; eas[tid][1] = a1; eas[tid][2] = a2;
            float nt = x[(size_t)s * IN_CH];   // node type of source (exact fp32)
            float mk;
            if (nt == 0.0f)      mk = (a0 < 0.5f) ? 1.0f : 0.0f;
            else if (nt == 1.0f) mk = (a0 < 0.3f) ? 1.0f : 0.0f;
            else                 mk = 1.0f;
            masks[tid] = mk;
            if (mk != 0.0f) unsafeAtomicAdd(&cnt[d], 1.0f);
        }
        __syncthreads();

        const int ebase = wave * 32;

        // ---- acc init: b1 + ea @ W1[128:131] (fp32 VALU) ----
        f32x4 acc1[2][4];
#pragma unroll
        for (int mt = 0; mt < 2; ++mt) {
            float e0[4], e1[4], e2[4];
#pragma unroll
            for (int r = 0; r < 4; ++r) {
                int el = ebase + mt * 16 + q * 4 + r;   // C-layout row
                e0[r] = eas[el][0]; e1[r] = eas[el][1]; e2[r] = eas[el][2];
            }
#pragma unroll
            for (int nt = 0; nt < 4; ++nt) {
                int n = nt * 16 + m16;                  // C-layout col
                float t0 = w1tail[0][n], t1 = w1tail[1][n];
                float t2 = w1tail[2][n], bb = w1tail[3][n];
#pragma unroll
                for (int r = 0; r < 4; ++r)
                    acc1[mt][nt][r] = bb + e0[r] * t0 + e1[r] * t1 + e2[r] * t2;
            }
        }

        // K=128 over [x_dst (kc 0,1) | x_src (kc 2,3)], A-frags from global bf16
#pragma unroll
        for (int kc = 0; kc < 4; ++kc) {
            bf16x8 af[2];
#pragma unroll
            for (int mt = 0; mt < 2; ++mt) {
                int el   = ebase + mt * 16 + m16;       // A-layout row m=lane&15
                int node = (kc < 2) ? dsts[el] : srcs[el];
                af[mt] = *reinterpret_cast<const bf16x8*>(
                    xb + (size_t)node * IN_CH + (kc & 1) * 32 + q * 8);
            }
#pragma unroll
            for (int nt = 0; nt < 4; ++nt) {
                bf16x8 bfr = *reinterpret_cast<const bf16x8*>(
                    &W1T[nt * 16 + m16][kc * 32 + q * 8]);
                acc1[0][nt] = __builtin_amdgcn_mfma_f32_16x16x32_bf16(af[0], bfr, acc1[0][nt], 0, 0, 0);
                acc1[1][nt] = __builtin_amdgcn_mfma_f32_16x16x32_bf16(af[1], bfr, acc1[1][nt], 0, 0, 0);
            }
        }

        // ---- epilogue: masked relu(h) -> packed fp16 atomics, zero-skip ----
#pragma unroll
        for (int mt = 0; mt < 2; ++mt) {
#pragma unroll
            for (int r = 0; r < 4; ++r) {
                int el = ebase + mt * 16 + q * 4 + r;   // C-layout row
                float mk = masks[el];
                if (mk != 0.0f) {
                    unsigned int* hbase = hsum + (size_t)dsts[el] * 32;
                    float v0 = acc1[mt][0][r]; v0 = v0 > 0.f ? v0 : 0.f;
                    float v1 = acc1[mt][1][r]; v1 = v1 > 0.f ? v1 : 0.f;
                    float v2 = acc1[mt][2][r]; v2 = v2 > 0.f ? v2 : 0.f;
                    float v3 = acc1[mt][3][r]; v3 = v3 > 0.f ? v3 : 0.f;
                    if (v0 + v1 > 0.f) {   // pair (m16, m16+16) -> dword m16
                        f16x2 p01 = {(_Float16)v0, (_Float16)v1};
                        atomic_pk_add_f16(hbase + m16, p01);
                    }
                    if (v2 + v3 > 0.f) {   // pair (m16+32, m16+48) -> dword 16+m16
                        f16x2 p23 = {(_Float16)v2, (_Float16)v3};
                        atomic_pk_add_f16(hbase + 16 + m16, p23);
                    }
                }
            }
        }
    }
}

// Node kernel (MFMA): out[n] = relu(hsum[n] @ W2 + cnt[n]*b2).
// hsum is fp16 in permuted channel order pi(p); W2's rows are staged with the
// same permutation so the GEMM is oblivious to it.
__global__ __launch_bounds__(256, 4) void gnn_node_out(
    const _Float16* __restrict__ hsum,  // [N_NODES][64] fp16, permuted channels
    const float*    __restrict__ cnt,   // [N_NODES]
    const float*    __restrict__ W2,    // [64][128]
    const float*    __restrict__ b2,    // [128]
    float*          __restrict__ out)   // [N_NODES][128]
{
    __shared__ __align__(16) unsigned short W2T[128][72];  // W2T[n][p]=W2[pi(p)][n]
    __shared__ float b2s[128];

    const int tid  = threadIdx.x;
    const int wave = tid >> 6;
    const int lane = tid & 63;
    const int q    = lane >> 4;
    const int m16  = lane & 15;

    for (int idx = tid; idx < 64 * 128; idx += 256) {
        int p = idx >> 7, n = idx & 127;
        // pi(p): dword d=p>>1, half e=p&1; d<16 -> ch d+16e; d>=16 -> ch d+16+16e
        int ch = (p >> 1) + 16 * (p & 1) + ((p >= 32) ? 16 : 0);
        W2T[n][p] = f2bf(W2[ch * 128 + n]);
    }
    if (tid < 128) b2s[tid] = b2[tid];
    __syncthreads();

    const int nodeBase = (blockIdx.x * 4 + wave) * 32;
    if (nodeBase >= N_NODES) return;   // tail waves (no barriers below)

    f32x4 acc[2][8];
#pragma unroll
    for (int mt = 0; mt < 2; ++mt)
#pragma unroll
        for (int nt = 0; nt < 8; ++nt)
            acc[mt][nt] = (f32x4){0.0f, 0.0f, 0.0f, 0.0f};

#pragma unroll
    for (int kc = 0; kc < 2; ++kc) {
        bf16x8 af[2];
#pragma unroll
        for (int mt = 0; mt < 2; ++mt) {
            int node = nodeBase + mt * 16 + m16;       // A-layout row
            if (node >= N_NODES) node = N_NODES - 1;   // clamp; rows unused
            f16x8 h = *reinterpret_cast<const f16x8*>(
                hsum + (size_t)node * HID_CH + kc * 32 + q * 8);
            union { bf16x8 v; unsigned short u[8]; } rr;
#pragma unroll
            for (int j = 0; j < 8; ++j) rr.u[j] = f2bf((float)h[j]);
            af[mt] = rr.v;
        }
#pragma unroll
        for (int nt = 0; nt < 8; ++nt) {
            bf16x8 bfr = *reinterpret_cast<const bf16x8*>(
                &W2T[nt * 16 + m16][kc * 32 + q * 8]);
            acc[0][nt] = __builtin_amdgcn_mfma_f32_16x16x32_bf16(af[0], bfr, acc[0][nt], 0, 0, 0);
            acc[1][nt] = __builtin_amdgcn_mfma_f32_16x16x32_bf16(af[1], bfr, acc[1][nt], 0, 0, 0);
        }
    }

    // epilogue: + cnt*b2, relu, store (C-layout: row=q*4+r, col=nt*16+m16)
#pragma unroll
    for (int mt = 0; mt < 2; ++mt) {
        float cc[4]; int nn[4];
#pragma unroll
        for (int r = 0; r < 4; ++r) {
            nn[r] = nodeBase + mt * 16 + q * 4 + r;
            cc[r] = (nn[r] < N_NODES) ? cnt[nn[r]] : 0.0f;
        }
#pragma unroll
        for (int nt = 0; nt < 8; ++nt) {
            int col = nt * 16 + m16;
            float bb = b2s[col];
#pragma unroll
            for (int r = 0; r < 4; ++r) {
                if (nn[r] < N_NODES) {
                    float v = acc[mt][nt][r] + cc[r] * bb;
                    out[(size_t)nn[r] * OUT_CH + col] = v > 0.0f ? v : 0.0f;
                }
            }
        }
    }
}

extern "C" void kernel_launch(void* const* d_in, const int* in_sizes, int n_in,
                              void* d_out, int out_size, void* d_ws, size_t ws_size,
                              hipStream_t stream) {
    const float* x  = (const float*)d_in[0];
    const int*   ei = (const int*)d_in[1];
    const float* ea = (const float*)d_in[2];
    const float* W1 = (const float*)d_in[3];
    const float* b1 = (const float*)d_in[4];
    const float* W2 = (const float*)d_in[5];
    const float* b2 = (const float*)d_in[6];
    float* out = (float*)d_out;

    // ws layout: [hsum fp16 12.8MB][cnt 0.4MB][xb bf16 12.8MB]  (26MB)
    char* wsb = (char*)d_ws;
    unsigned int*   hsum = (unsigned int*)wsb;                    // packed pairs
    float*          cnt  = (float*)(wsb + 12800000);
    unsigned short* xb   = (unsigned short*)(wsb + 13200000);

    // fused prep: x->bf16 + zero hsum/cnt (ws re-poisoned before every call)
    gnn_prep<<<(2425000 + 255) / 256, 256, 0, stream>>>(
        x, xb, (uint4*)hsum, (float4*)cnt);

    // 1024 blocks = 4 blocks/CU — edge MLP layer 1 + packed-f16 hidden scatter
    gnn_edge_hidden<<<1024, 256, 0, stream>>>(x, xb, ei, ea, W1, b1, hsum, cnt);

    // node-level layer 2 + relu via MFMA: 128 nodes/block, 782 blocks
    gnn_node_out<<<(N_NODES + 127) / 128, 256, 0, stream>>>(
        (const _Float16*)hsum, cnt, W2, b2, out);
}

// Round 6
// 280.807 us; speedup vs baseline: 1.9826x; 1.0023x over previous
//
#include <hip/hip_runtime.h>

#define N_NODES 100000
#define N_EDGES 1600000
#define IN_CH   64
#define HID_CH  64
#define OUT_CH  128
#define TILE    128
#define N_TILES (N_EDGES / TILE)   // 12500 exactly

typedef __attribute__((ext_vector_type(8))) __bf16    bf16x8;
typedef __attribute__((ext_vector_type(4))) float     f32x4;
typedef __attribute__((ext_vector_type(2))) _Float16  f16x2;
typedef __attribute__((ext_vector_type(8))) _Float16  f16x8;

__device__ __forceinline__ unsigned short f2bf(float f) {
    union { float f; unsigned int i; } c;
    c.f = f;
    unsigned int u = c.i;
    unsigned int r = (u + 0x7FFFu + ((u >> 16) & 1u)) >> 16;   // RNE
    return (unsigned short)r;
}

// packed fp16 atomic add (global_atomic_pk_add_f16, gfx90a+)
__device__ __forceinline__ void atomic_pk_add_f16(unsigned int* addr, f16x2 val) {
    typedef __attribute__((address_space(1))) f16x2 gf16x2;
    __builtin_amdgcn_global_atomic_fadd_v2f16((gf16x2*)(void*)addr, val);
}

// fused prep: x fp32->bf16 convert + node-type byte table + zero hsum/cnt.
// items: [0,1.6M): x float4 convert (writes ntype byte when col==0);
//        [1.6M,2.4M): hsum uint4 zero; [2.4M,2.425M): cnt float4 zero
__global__ void gnn_prep(const float* __restrict__ xf,
                         unsigned short* __restrict__ xb,
                         unsigned char* __restrict__ ntype,  // [N_NODES]
                         uint4* __restrict__ hz,      // hsum as uint4 (800k)
                         float4* __restrict__ cz) {   // cnt  as float4 (25k)
    int i = blockIdx.x * blockDim.x + threadIdx.x;
    if (i < 1600000) {
        float4 v = reinterpret_cast<const float4*>(xf)[i];
        ushort4 o;
        o.x = f2bf(v.x); o.y = f2bf(v.y); o.z = f2bf(v.z); o.w = f2bf(v.w);
        reinterpret_cast<ushort4*>(xb)[i] = o;
        if ((i & 15) == 0) {   // this vec4 holds cols 0..3 of node i/16
            int n = i >> 4;
            ntype[n] = (v.x == 0.0f) ? 0 : ((v.x == 1.0f) ? 1 : 2);
        }
    } else if (i < 2400000) {
        hz[i - 1600000] = (uint4){0u, 0u, 0u, 0u};
    } else if (i < 2425000) {
        cz[i - 2400000] = (float4){0.f, 0.f, 0.f, 0.f};
    }
}

// Edge kernel: h_e = relu([x_dst|x_src|ea] @ W1 + b1); masked scatter of the
// 64-ch hidden into hsum[dst] as PACKED fp16 atomics (2 ch/dword), skipping
// all-zero pairs (~25% post-relu). Mask uses the 100KB node-type byte table
// (L2-resident) instead of random 4B reads into the 25.6MB x array — that
// gather was ~220MB of the 267MB FETCH_SIZE in round 5.
// hsum channel order is permuted (dword d<16 -> ch (d,d+16); d>=16 ->
// (d+16,d+32)); the node kernel permutes W2's rows identically.
__global__ __launch_bounds__(256, 4) void gnn_edge_hidden(
    const unsigned char*  __restrict__ ntype, // [N_NODES] node type 0/1/2
    const unsigned short* __restrict__ xb,    // [N_NODES][64] bf16 bits
    const int*            __restrict__ eidx,  // [2][N_EDGES]
    const float*          __restrict__ ea,    // [N_EDGES][3]
    const float*          __restrict__ W1,    // [131][64]
    const float*          __restrict__ b1,    // [64]
    unsigned int*         __restrict__ hsum,  // [N_NODES][32] packed-f16 pairs
    float*                __restrict__ cnt)   // [N_NODES] masked-edge counts
{
    __shared__ __align__(16) unsigned short W1T[64][136];   // W1T[n][k]=W1[k][n], k<128
    __shared__ float w1tail[4][64];   // W1[128],W1[129],W1[130], b1 (fp32)
    __shared__ float eas[128][4];
    __shared__ float masks[128];
    __shared__ int   dsts[128];
    __shared__ int   srcs[128];

    const int tid  = threadIdx.x;
    const int wave = tid >> 6;
    const int lane = tid & 63;
    const int q    = lane >> 4;   // quad 0..3
    const int m16  = lane & 15;

    // ---- stage W1 once per persistent block (fp32 -> bf16) ----
    for (int idx = tid; idx < 128 * 64; idx += 256) {
        int k = idx >> 6, n = idx & 63;
        W1T[n][k] = f2bf(W1[idx]);
    }
    if (tid < 64) {
        w1tail[0][tid] = W1[128 * 64 + tid];
        w1tail[1][tid] = W1[129 * 64 + tid];
        w1tail[2][tid] = W1[130 * 64 + tid];
        w1tail[3][tid] = b1[tid];
    }

    for (int t = blockIdx.x; t < N_TILES; t += gridDim.x) {
        __syncthreads();   // covers weight staging (1st iter) + LDS WAR reuse
        if (tid < 128) {
            int e = t * TILE + tid;
            int s = eidx[e];
            int d = eidx[N_EDGES + e];
            srcs[tid] = s;
            dsts[tid] = d;
            float a0 = ea[e * 3 + 0];
            float a1 = ea[e * 3 + 1];
            float a2 = ea[e * 3 + 2];
            eas[tid][0] = a0; eas[tid][1] = a1; eas[tid][2] = a2;
            int ntc = ntype[s];   // 1-byte type, L2-resident table
            float mk;
            if (ntc == 0)      mk = (a0 < 0.5f) ? 1.0f : 0.0f;
            else if (ntc == 1) mk = (a0 < 0.3f) ? 1.0f : 0.0f;
            else               mk = 1.0f;
            masks[tid] = mk;
            if (mk != 0.0f) unsafeAtomicAdd(&cnt[d], 1.0f);
        }
        __syncthreads();

        const int ebase = wave * 32;

        // ---- acc init: b1 + ea @ W1[128:131] (fp32 VALU) ----
        f32x4 acc1[2][4];
#pragma unroll
        for (int mt = 0; mt < 2; ++mt) {
            float e0[4], e1[4], e2[4];
#pragma unroll
            for (int r = 0; r < 4; ++r) {
                int el = ebase + mt * 16 + q * 4 + r;   // C-layout row
                e0[r] = eas[el][0]; e1[r] = eas[el][1]; e2[r] = eas[el][2];
            }
#pragma unroll
            for (int nt = 0; nt < 4; ++nt) {
                int n = nt * 16 + m16;                  // C-layout col
                float t0 = w1tail[0][n], t1 = w1tail[1][n];
                float t2 = w1tail[2][n], bb = w1tail[3][n];
#pragma unroll
                for (int r = 0; r < 4; ++r)
                    acc1[mt][nt][r] = bb + e0[r] * t0 + e1[r] * t1 + e2[r] * t2;
            }
        }

        // K=128 over [x_dst (kc 0,1) | x_src (kc 2,3)], A-frags from global bf16
#pragma unroll
        for (int kc = 0; kc < 4; ++kc) {
            bf16x8 af[2];
#pragma unroll
            for (int mt = 0; mt < 2; ++mt) {
                int el   = ebase + mt * 16 + m16;       // A-layout row m=lane&15
                int node = (kc < 2) ? dsts[el] : srcs[el];
                af[mt] = *reinterpret_cast<const bf16x8*>(
                    xb + (size_t)node * IN_CH + (kc & 1) * 32 + q * 8);
            }
#pragma unroll
            for (int nt = 0; nt < 4; ++nt) {
                bf16x8 bfr = *reinterpret_cast<const bf16x8*>(
                    &W1T[nt * 16 + m16][kc * 32 + q * 8]);
                acc1[0][nt] = __builtin_amdgcn_mfma_f32_16x16x32_bf16(af[0], bfr, acc1[0][nt], 0, 0, 0);
                acc1[1][nt] = __builtin_amdgcn_mfma_f32_16x16x32_bf16(af[1], bfr, acc1[1][nt], 0, 0, 0);
            }
        }

        // ---- epilogue: masked relu(h) -> packed fp16 atomics, zero-skip ----
#pragma unroll
        for (int mt = 0; mt < 2; ++mt) {
#pragma unroll
            for (int r = 0; r < 4; ++r) {
                int el = ebase + mt * 16 + q * 4 + r;   // C-layout row
                float mk = masks[el];
                if (mk != 0.0f) {
                    unsigned int* hbase = hsum + (size_t)dsts[el] * 32;
                    float v0 = acc1[mt][0][r]; v0 = v0 > 0.f ? v0 : 0.f;
                    float v1 = acc1[mt][1][r]; v1 = v1 > 0.f ? v1 : 0.f;
                    float v2 = acc1[mt][2][r]; v2 = v2 > 0.f ? v2 : 0.f;
                    float v3 = acc1[mt][3][r]; v3 = v3 > 0.f ? v3 : 0.f;
                    if (v0 + v1 > 0.f) {   // pair (m16, m16+16) -> dword m16
                        f16x2 p01 = {(_Float16)v0, (_Float16)v1};
                        atomic_pk_add_f16(hbase + m16, p01);
                    }
                    if (v2 + v3 > 0.f) {   // pair (m16+32, m16+48) -> dword 16+m16
                        f16x2 p23 = {(_Float16)v2, (_Float16)v3};
                        atomic_pk_add_f16(hbase + 16 + m16, p23);
                    }
                }
            }
        }
    }
}

// Node kernel (MFMA): out[n] = relu(hsum[n] @ W2 + cnt[n]*b2).
// hsum is fp16 in permuted channel order pi(p); W2's rows are staged with the
// same permutation so the GEMM is oblivious to it.
__global__ __launch_bounds__(256, 4) void gnn_node_out(
    const _Float16* __restrict__ hsum,  // [N_NODES][64] fp16, permuted channels
    const float*    __restrict__ cnt,   // [N_NODES]
    const float*    __restrict__ W2,    // [64][128]
    const float*    __restrict__ b2,    // [128]
    float*          __restrict__ out)   // [N_NODES][128]
{
    __shared__ __align__(16) unsigned short W2T[128][72];  // W2T[n][p]=W2[pi(p)][n]
    __shared__ float b2s[128];

    const int tid  = threadIdx.x;
    const int wave = tid >> 6;
    const int lane = tid & 63;
    const int q    = lane >> 4;
    const int m16  = lane & 15;

    for (int idx = tid; idx < 64 * 128; idx += 256) {
        int p = idx >> 7, n = idx & 127;
        // pi(p): dword d=p>>1, half e=p&1; d<16 -> ch d+16e; d>=16 -> ch d+16+16e
        int ch = (p >> 1) + 16 * (p & 1) + ((p >= 32) ? 16 : 0);
        W2T[n][p] = f2bf(W2[ch * 128 + n]);
    }
    if (tid < 128) b2s[tid] = b2[tid];
    __syncthreads();

    const int nodeBase = (blockIdx.x * 4 + wave) * 32;
    if (nodeBase >= N_NODES) return;   // tail waves (no barriers below)

    f32x4 acc[2][8];
#pragma unroll
    for (int mt = 0; mt < 2; ++mt)
#pragma unroll
        for (int nt = 0; nt < 8; ++nt)
            acc[mt][nt] = (f32x4){0.0f, 0.0f, 0.0f, 0.0f};

#pragma unroll
    for (int kc = 0; kc < 2; ++kc) {
        bf16x8 af[2];
#pragma unroll
        for (int mt = 0; mt < 2; ++mt) {
            int node = nodeBase + mt * 16 + m16;       // A-layout row
            if (node >= N_NODES) node = N_NODES - 1;   // clamp; rows unused
            f16x8 h = *reinterpret_cast<const f16x8*>(
                hsum + (size_t)node * HID_CH + kc * 32 + q * 8);
            union { bf16x8 v; unsigned short u[8]; } rr;
#pragma unroll
            for (int j = 0; j < 8; ++j) rr.u[j] = f2bf((float)h[j]);
            af[mt] = rr.v;
        }
#pragma unroll
        for (int nt = 0; nt < 8; ++nt) {
            bf16x8 bfr = *reinterpret_cast<const bf16x8*>(
                &W2T[nt * 16 + m16][kc * 32 + q * 8]);
            acc[0][nt] = __builtin_amdgcn_mfma_f32_16x16x32_bf16(af[0], bfr, acc[0][nt], 0, 0, 0);
            acc[1][nt] = __builtin_amdgcn_mfma_f32_16x16x32_bf16(af[1], bfr, acc[1][nt], 0, 0, 0);
        }
    }

    // epilogue: + cnt*b2, relu, store (C-layout: row=q*4+r, col=nt*16+m16)
#pragma unroll
    for (int mt = 0; mt < 2; ++mt) {
        float cc[4]; int nn[4];
#pragma unroll
        for (int r = 0; r < 4; ++r) {
            nn[r] = nodeBase + mt * 16 + q * 4 + r;
            cc[r] = (nn[r] < N_NODES) ? cnt[nn[r]] : 0.0f;
        }
#pragma unroll
        for (int nt = 0; nt < 8; ++nt) {
            int col = nt * 16 + m16;
            float bb = b2s[col];
#pragma unroll
            for (int r = 0; r < 4; ++r) {
                if (nn[r] < N_NODES) {
                    float v = acc[mt][nt][r] + cc[r] * bb;
                    out[(size_t)nn[r] * OUT_CH + col] = v > 0.0f ? v : 0.0f;
                }
            }
        }
    }
}

extern "C" void kernel_launch(void* const* d_in, const int* in_sizes, int n_in,
                              void* d_out, int out_size, void* d_ws, size_t ws_size,
                              hipStream_t stream) {
    const float* x  = (const float*)d_in[0];
    const int*   ei = (const int*)d_in[1];
    const float* ea = (const float*)d_in[2];
    const float* W1 = (const float*)d_in[3];
    const float* b1 = (const float*)d_in[4];
    const float* W2 = (const float*)d_in[5];
    const float* b2 = (const float*)d_in[6];
    float* out = (float*)d_out;

    // ws layout: [hsum fp16 12.8MB][cnt 0.4MB][xb bf16 12.8MB][ntype 0.1MB]
    char* wsb = (char*)d_ws;
    unsigned int*   hsum  = (unsigned int*)wsb;                   // packed pairs
    float*          cnt   = (float*)(wsb + 12800000);
    unsigned short* xb    = (unsigned short*)(wsb + 13200000);
    unsigned char*  ntype = (unsigned char*)(wsb + 26000000);

    // fused prep: x->bf16 + node-type table + zero hsum/cnt
    gnn_prep<<<(2425000 + 255) / 256, 256, 0, stream>>>(
        x, xb, ntype, (uint4*)hsum, (float4*)cnt);

    // 1792 blocks = 7 blocks/CU (LDS limit at 22KB) — layer 1 + f16 scatter
    gnn_edge_hidden<<<1792, 256, 0, stream>>>(ntype, xb, ei, ea, W1, b1, hsum, cnt);

    // node-level layer 2 + relu via MFMA: 128 nodes/block, 782 blocks
    gnn_node_out<<<(N_NODES + 127) / 128, 256, 0, stream>>>(
        (const _Float16*)hsum, cnt, W2, b2, out);
}